// Round 6
// baseline (2999.339 us; speedup 1.0000x reference)
//
#include <hip/hip_runtime.h>

// LSTM B=1024, T=256, H=256, fp32. v6: wave-local k-reduction design.
// Grid 256 = 64 rowgroups (16 rows) x 4 colgroups (64 hcols). Block = 1024 thr
// = 16 waves; wave covers 4 hcols x 16 rows. Phase A: lane (hcA=lane>>4,
// ks=lane&15) holds 4 gates x 16 k weights (64 VGPR - the allocator-safe size;
// 128+ was repeatedly spilled in v1/v4/v5). DPP row_ror:8 pre-reduces k-pairs,
// per-WAVE part[] LDS finishes; phase B remaps all 64 lanes to (row, hcol,
// gate) tasks: one sigmoid path per lane (tanh = 2*sig(2x)-1), quad_perm
// gathers gates, c redundant per quad. 2 __syncthreads per step. Cross-block
// h exchange: per-access agent-scope coherent loads/stores + per-cg monotonic
// flags (per-wave spins). Partner blocks of a rowgroup share an XCD (bid&7).

#define Bsz   1024
#define Tt    256
#define Hh    256
#define NCLS  10
#define RGR   16
#define NRG   64
#define NCG   4
#define NTHR  1024
#define HSZ   ((size_t)Bsz * Hh)
#define HST   320               // htile row stride: 16 chunks x (16+4 pad)
#define PST   160               // part row stride: 8 ks x 20

typedef __attribute__((ext_vector_type(2))) float f32x2;
typedef unsigned long long u64;

template<int CTRL>
__device__ __forceinline__ float dpp_movf(float v) {
    return __builtin_bit_cast(float,
        __builtin_amdgcn_update_dpp(0, __builtin_bit_cast(int, v),
                                    CTRL, 0xF, 0xF, true));
}

__device__ __forceinline__ float fast_tanh(float v) {
    const float e = __expf(-2.0f * fabsf(v));
    const float t = (1.0f - e) * __builtin_amdgcn_rcpf(1.0f + e);
    return copysignf(t, v);
}

__device__ __forceinline__ u64 coh_load64(const u64* p) {
    return __hip_atomic_load((u64*)p, __ATOMIC_RELAXED, __HIP_MEMORY_SCOPE_AGENT);
}
__device__ __forceinline__ unsigned coh_load32(const unsigned* p) {
    return __hip_atomic_load((unsigned*)p, __ATOMIC_RELAXED, __HIP_MEMORY_SCOPE_AGENT);
}
__device__ __forceinline__ void coh_storef(float* p, float v) {
    __hip_atomic_store(p, v, __ATOMIC_RELAXED, __HIP_MEMORY_SCOPE_AGENT);
}

extern "C" __global__ void __launch_bounds__(NTHR, 4)
lstm_v6(const float* __restrict__ x,
        const float* __restrict__ W_gx, const float* __restrict__ W_gh, const float* __restrict__ b_g,
        const float* __restrict__ W_ix, const float* __restrict__ W_ih, const float* __restrict__ b_i,
        const float* __restrict__ W_fx, const float* __restrict__ W_fh, const float* __restrict__ b_f,
        const float* __restrict__ W_ox, const float* __restrict__ W_oh, const float* __restrict__ b_o,
        const float* __restrict__ W_ph, const float* __restrict__ b_p,
        float* __restrict__ out, float* __restrict__ hbuf, unsigned* __restrict__ fcnt)
{
    __shared__ float htile[RGR][HST];     // 20 KB  (16 chunks of 16 cols + 4 pad)
    __shared__ float part[16][4 * PST];   // 40 KB  per-wave: [rl][ks<8][hc][g]

    const int tid  = threadIdx.x;
    const int lane = tid & 63;
    const int wv   = tid >> 6;
    const int rg   = blockIdx.x & 63;     // partners {rg, 64+rg, 128+rg, 192+rg} same XCD
    const int cg   = blockIdx.x >> 6;
    const int r0   = rg * RGR;

    // ---- phase-A roles: lane = (hcA, ks); 64 weights in regs ----
    const int hcA = lane >> 4;
    const int ks  = lane & 15;
    const int jA  = cg * 64 + wv * 4 + hcA;

    const float* __restrict__ Wg[4] = {W_gh, W_ih, W_fh, W_oh};
    f32x2 w2[4][8];
    #pragma unroll
    for (int g = 0; g < 4; ++g) {
        const float* __restrict__ src = Wg[g] + (size_t)(16 * ks) * Hh + jA;
        #pragma unroll
        for (int p = 0; p < 8; ++p) {
            f32x2 t2;
            t2.x = src[(size_t)(2 * p) * Hh];
            t2.y = src[(size_t)(2 * p + 1) * Hh];
            w2[g][p] = t2;
        }
    }

    // ---- phase-B roles: lane = (rl, hcB, g) ----
    const int rl  = lane >> 4;
    const int hcB = (lane >> 2) & 3;
    const int g   = lane & 3;
    const int jB  = cg * 64 + wv * 4 + hcB;
    // reference bias swap preserved: f-gate (g==2) uses b_o, o-gate (g==3) uses b_f
    const float* __restrict__ Wx[4] = {W_gx, W_ix, W_fx, W_ox};
    const float* __restrict__ Bb[4] = {b_g, b_i, b_o, b_f};
    const float wx1 = Wx[g][jB];
    const float bb1 = Bb[g][jB];
    float c_st[4];
    #pragma unroll
    for (int ch = 0; ch < 4; ++ch) c_st[ch] = 0.0f;

    unsigned* fbase = fcnt + rg * NCG;

    // htile = h_0 = 0
    for (int i = tid; i < RGR * HST; i += NTHR) (&htile[0][0])[i] = 0.0f;
    __syncthreads();

    // staging role (u64 granularity)
    const int srow = (tid & 511) >> 5;    // 0..15
    const int c2   = tid & 31;            // u64 within a 64-col group

    for (int t = 0; t < Tt; ++t) {
        const float* hcur = hbuf + ((t & 1) ? HSZ : 0);
        float*       hnxt = hbuf + ((t & 1) ? 0 : HSZ);

        // ---- stage 3 foreign 64-col slices (each 512 u64) ----
        {
            const int fc1 = tid >> 9;                       // wave-uniform
            const int fcg1 = fc1 + (fc1 >= cg ? 1 : 0);
            if (t > 0)
                while (coh_load32(fbase + fcg1) < (unsigned)t) __builtin_amdgcn_s_sleep(1);
            u64 v = coh_load64((const u64*)hcur + (size_t)(r0 + srow) * 128 + fcg1 * 32 + c2);
            ((u64*)&htile[0][0])[srow * 160 + (fcg1 * 4 + (c2 >> 3)) * 10 + (c2 & 7)] = v;
            if (tid < 512) {
                const int fcg2 = 2 + (2 >= cg ? 1 : 0);
                if (t > 0)
                    while (coh_load32(fbase + fcg2) < (unsigned)t) __builtin_amdgcn_s_sleep(1);
                u64 v2 = coh_load64((const u64*)hcur + (size_t)(r0 + srow) * 128 + fcg2 * 32 + c2);
                ((u64*)&htile[0][0])[srow * 160 + (fcg2 * 4 + (c2 >> 3)) * 10 + (c2 & 7)] = v2;
            }
        }
        __syncthreads();                                     // htile = h(t) complete

        // ---- 4 chunks of 4 rows: phase A -> wave-local reduce -> phase B ----
        #pragma unroll
        for (int ch = 0; ch < 4; ++ch) {
            const float xval = x[(size_t)(r0 + 4 * ch + rl) * Tt + t];  // phase-B row

            #pragma unroll
            for (int rr = 0; rr < 4; ++rr) {
                const float* hb = &htile[4 * ch + rr][ks * 20];
                const float4 q0 = *reinterpret_cast<const float4*>(hb + 0);
                const float4 q1 = *reinterpret_cast<const float4*>(hb + 4);
                const float4 q2 = *reinterpret_cast<const float4*>(hb + 8);
                const float4 q3 = *reinterpret_cast<const float4*>(hb + 12);
                f32x2 h0; h0.x = q0.x; h0.y = q0.y;
                f32x2 h1; h1.x = q0.z; h1.y = q0.w;
                f32x2 h2; h2.x = q1.x; h2.y = q1.y;
                f32x2 h3; h3.x = q1.z; h3.y = q1.w;
                f32x2 h4; h4.x = q2.x; h4.y = q2.y;
                f32x2 h5; h5.x = q2.z; h5.y = q2.w;
                f32x2 h6; h6.x = q3.x; h6.y = q3.y;
                f32x2 h7; h7.x = q3.z; h7.y = q3.w;

                float4 sv;
                #pragma unroll
                for (int gg = 0; gg < 4; ++gg) {
                    f32x2 a; a.x = 0.0f; a.y = 0.0f;
                    a = __builtin_elementwise_fma(h0, w2[gg][0], a);
                    a = __builtin_elementwise_fma(h1, w2[gg][1], a);
                    a = __builtin_elementwise_fma(h2, w2[gg][2], a);
                    a = __builtin_elementwise_fma(h3, w2[gg][3], a);
                    a = __builtin_elementwise_fma(h4, w2[gg][4], a);
                    a = __builtin_elementwise_fma(h5, w2[gg][5], a);
                    a = __builtin_elementwise_fma(h6, w2[gg][6], a);
                    a = __builtin_elementwise_fma(h7, w2[gg][7], a);
                    float s = a.x + a.y;
                    s += dpp_movf<0x128>(s);        // row_ror:8 -> pairwise k-sum
                    (&sv.x)[gg] = s;
                }
                if (ks < 8)
                    *reinterpret_cast<float4*>(&part[wv][rr * PST + ks * 20 + hcA * 4]) = sv;
            }

            // phase B: every lane finishes one gate of state (4ch+rl, hcB)
            const float* pp = &part[wv][rl * PST + hcB * 4 + g];
            float s = pp[0] + pp[20] + pp[40] + pp[60]
                    + pp[80] + pp[100] + pp[120] + pp[140];
            const float pre = s + fmaf(xval, wx1, bb1);
            // unified activation: tanh(p) = 2*sigmoid(2p) - 1
            const float v   = (g == 0) ? 2.0f * pre : pre;
            const float e   = __expf(-fabsf(v));
            const float pss = __builtin_amdgcn_rcpf(1.0f + e);
            const float y   = (v >= 0.0f) ? pss : 1.0f - pss;
            const float act = (g == 0) ? 2.0f * y - 1.0f : y;

            const float gv = dpp_movf<0x00>(act);   // quad lane 0: g
            const float iv = dpp_movf<0x55>(act);   // quad lane 1: i
            const float fv = dpp_movf<0xAA>(act);   // quad lane 2: f
            const float ov = dpp_movf<0xFF>(act);   // quad lane 3: o
            c_st[ch] = fmaf(gv, iv, c_st[ch] * fv);
            const float hv = fast_tanh(c_st[ch]) * ov;
            if (g == 0) {
                const int row = 4 * ch + rl;
                coh_storef(&hnxt[(size_t)(r0 + row) * Hh + jB], hv);
                htile[row][(jB >> 4) * 20 + (jB & 15)] = hv;
            }
        }

        __syncthreads();                  // drains vmcnt; htile stable for next stage
        if (tid == 0)
            __hip_atomic_store(fbase + cg, (unsigned)(t + 1),
                               __ATOMIC_RELEASE, __HIP_MEMORY_SCOPE_AGENT);
    }

    // ---- classifier (cg==0): stage foreign h_T, then out = h_T @ W_ph + b_p ----
    if (cg == 0) {
        const float* hT = hbuf;                       // Tt even -> h(256) in buffer 0
        const int fc1 = tid >> 9;
        const int fcg1 = fc1 + (fc1 >= cg ? 1 : 0);
        while (coh_load32(fbase + fcg1) < (unsigned)Tt) __builtin_amdgcn_s_sleep(1);
        u64 v = coh_load64((const u64*)hT + (size_t)(r0 + srow) * 128 + fcg1 * 32 + c2);
        ((u64*)&htile[0][0])[srow * 160 + (fcg1 * 4 + (c2 >> 3)) * 10 + (c2 & 7)] = v;
        if (tid < 512) {
            const int fcg2 = 2 + (2 >= cg ? 1 : 0);
            while (coh_load32(fbase + fcg2) < (unsigned)Tt) __builtin_amdgcn_s_sleep(1);
            u64 v2 = coh_load64((const u64*)hT + (size_t)(r0 + srow) * 128 + fcg2 * 32 + c2);
            ((u64*)&htile[0][0])[srow * 160 + (fcg2 * 4 + (c2 >> 3)) * 10 + (c2 & 7)] = v2;
        }
        __syncthreads();

        for (int idx = tid; idx < RGR * NCLS; idx += NTHR) {
            const int row = idx / NCLS;
            const int cc  = idx - row * NCLS;
            float a = b_p[cc];
            for (int k = 0; k < Hh; ++k)
                a = fmaf(htile[row][(k >> 4) * 20 + (k & 15)], W_ph[k * NCLS + cc], a);
            out[(size_t)(r0 + row) * NCLS + cc] = a;
        }
    }
}

extern "C" void kernel_launch(void* const* d_in, const int* in_sizes, int n_in,
                              void* d_out, int out_size, void* d_ws, size_t ws_size,
                              hipStream_t stream) {
    const float* x    = (const float*)d_in[0];
    const float* W_gx = (const float*)d_in[1];
    const float* W_gh = (const float*)d_in[2];
    const float* b_g  = (const float*)d_in[3];
    const float* W_ix = (const float*)d_in[4];
    const float* W_ih = (const float*)d_in[5];
    const float* b_i  = (const float*)d_in[6];
    const float* W_fx = (const float*)d_in[7];
    const float* W_fh = (const float*)d_in[8];
    const float* b_f  = (const float*)d_in[9];
    const float* W_ox = (const float*)d_in[10];
    const float* W_oh = (const float*)d_in[11];
    const float* b_o  = (const float*)d_in[12];
    const float* W_ph = (const float*)d_in[13];
    const float* b_p  = (const float*)d_in[14];
    float* out = (float*)d_out;

    float*    hbuf = (float*)d_ws;                       // 2 MB ping-pong
    unsigned* fcnt = (unsigned*)((char*)d_ws + 2 * HSZ * sizeof(float));
    const size_t clear_bytes = 2 * HSZ * sizeof(float) + NRG * NCG * sizeof(unsigned);

    hipMemsetAsync(d_ws, 0, clear_bytes, stream);        // h0 = 0 + flags = 0

    lstm_v6<<<dim3(NRG * NCG), dim3(NTHR), 0, stream>>>(
        x, W_gx, W_gh, b_g, W_ix, W_ih, b_i, W_fx, W_fh, b_f,
        W_ox, W_oh, b_o, W_ph, b_p, out, hbuf, fcnt);
}